// Round 1
// baseline (547.462 us; speedup 1.0000x reference)
//
#include <hip/hip_runtime.h>
#include <hip/hip_bf16.h>

typedef __bf16 bf16;
typedef __bf16 bf16x8 __attribute__((ext_vector_type(8)));
typedef __bf16 bf16x4 __attribute__((ext_vector_type(4)));
typedef float f32x4 __attribute__((ext_vector_type(4)));

#define CDIM 1280
#define SDIM 1024

static __device__ __forceinline__ f32x4 mfma16(bf16x8 a, bf16x8 b, f32x4 c) {
  return __builtin_amdgcn_mfma_f32_16x16x32_bf16(a, b, c, 0, 0, 0);
}

__global__ void cvt_kernel(const float* __restrict__ x, bf16* __restrict__ y, int n4) {
  int i = blockIdx.x * blockDim.x + threadIdx.x;
  if (i >= n4) return;
  float4 v = reinterpret_cast<const float4*>(x)[i];
  bf16x4 o;
  o.x = (bf16)v.x; o.y = (bf16)v.y; o.z = (bf16)v.z; o.w = (bf16)v.w;
  reinterpret_cast<bf16x4*>(y)[i] = o;
}

// Y[row][col] = sum_k X[row][k] * W[col][k]   (X: Mx1280, W: 1280x1280, both bf16)
// optional gate[row] multiplier (f32), optional f32 output with bias[col].
__global__ __launch_bounds__(256) void gemm_bt(const bf16* __restrict__ X,
                                               const bf16* __restrict__ W,
                                               bf16* __restrict__ Ybf,
                                               float* __restrict__ Yf,
                                               const float* __restrict__ gate,
                                               const float* __restrict__ bias) {
  const int lane = threadIdx.x & 63;
  const int wv = threadIdx.x >> 6;
  const int lr = lane & 15, lg = lane >> 4;
  const int rbase = blockIdx.y * 128 + (wv >> 1) * 64;
  const int cbase = blockIdx.x * 128 + (wv & 1) * 64;
  f32x4 acc[4][4] = {};
  const bf16* Xp = X + (size_t)(rbase + lr) * CDIM + lg * 8;
  const bf16* Wp = W + (size_t)(cbase + lr) * CDIM + lg * 8;
  for (int k = 0; k < CDIM; k += 32) {
    bf16x8 a[4], b[4];
#pragma unroll
    for (int i = 0; i < 4; ++i) {
      a[i] = *reinterpret_cast<const bf16x8*>(Xp + (size_t)i * 16 * CDIM + k);
      b[i] = *reinterpret_cast<const bf16x8*>(Wp + (size_t)i * 16 * CDIM + k);
    }
#pragma unroll
    for (int i = 0; i < 4; ++i)
#pragma unroll
      for (int j = 0; j < 4; ++j)
        acc[i][j] = mfma16(a[i], b[j], acc[i][j]);
  }
#pragma unroll
  for (int i = 0; i < 4; ++i) {
#pragma unroll
    for (int r = 0; r < 4; ++r) {
      const int row = rbase + i * 16 + lg * 4 + r;
      const float g = gate ? gate[row] : 1.0f;
#pragma unroll
      for (int j = 0; j < 4; ++j) {
        const int col = cbase + j * 16 + lr;
        const float v = acc[i][j][r] * g;
        if (Ybf) Ybf[(size_t)row * CDIM + col] = (bf16)v;
        else     Yf[(size_t)row * CDIM + col] = v + bias[col];
      }
    }
  }
}

// One block per (b, h, 64-row q tile). 4 waves, each owns 16 q-rows.
// Two branches (bg, face) with independent online softmax; outputs summed.
__global__ __launch_bounds__(256) void attn_kernel(const bf16* __restrict__ Q,
                                                   const bf16* __restrict__ Kbg,
                                                   const bf16* __restrict__ Vbg,
                                                   const bf16* __restrict__ Kf,
                                                   const bf16* __restrict__ Vf,
                                                   bf16* __restrict__ Mg) {
  __shared__ bf16 Klds[64 * 72];
  __shared__ bf16 VT[64 * 72];   // VT[d][key]
  __shared__ bf16 Plds[64 * 72]; // P[q][key], per-wave 16-row slices
  const int tid = threadIdx.x;
  const int lane = tid & 63, wv = tid >> 6;
  const int lr = lane & 15, lg = lane >> 4;
  const int qt = blockIdx.x, h = blockIdx.y, b = blockIdx.z;
  const int qrow = b * 2048 + qt * 64 + wv * 16;

  bf16x8 qf[2];
  {
    const bf16* qp = Q + (size_t)(qrow + lr) * CDIM + h * 64 + lg * 8;
    qf[0] = *reinterpret_cast<const bf16x8*>(qp);
    qf[1] = *reinterpret_cast<const bf16x8*>(qp + 32);
  }

  f32x4 Ofin[4] = {};
  const bf16* Ks[2] = {Kbg, Kf};
  const bf16* Vs[2] = {Vbg, Vf};

  for (int br = 0; br < 2; ++br) {
    const bf16* Kp = Ks[br];
    const bf16* Vp = Vs[br];
    float m[4] = {-INFINITY, -INFINITY, -INFINITY, -INFINITY};
    float lsum[4] = {0.f, 0.f, 0.f, 0.f};
    f32x4 O[4] = {};

    for (int kt = 0; kt < 16; ++kt) {
      __syncthreads();
      { // stage K tile [64 keys][64 d]
        const int row = tid >> 2, cs = (tid & 3) * 16;
        const bf16* src = Kp + (size_t)(b * 1024 + kt * 64 + row) * CDIM + h * 64 + cs;
        *reinterpret_cast<bf16x8*>(&Klds[row * 72 + cs]) = *reinterpret_cast<const bf16x8*>(src);
        *reinterpret_cast<bf16x8*>(&Klds[row * 72 + cs + 8]) = *reinterpret_cast<const bf16x8*>(src + 8);
      }
      { // stage V transposed: VT[d][key]
        const int key = tid & 63, dh = tid >> 6;
        const bf16* src = Vp + (size_t)(b * 1024 + kt * 64 + key) * CDIM + h * 64 + dh * 16;
        bf16x8 v0 = *reinterpret_cast<const bf16x8*>(src);
        bf16x8 v1 = *reinterpret_cast<const bf16x8*>(src + 8);
#pragma unroll
        for (int j = 0; j < 8; ++j) {
          VT[(dh * 16 + j) * 72 + key] = v0[j];
          VT[(dh * 16 + 8 + j) * 72 + key] = v1[j];
        }
      }
      __syncthreads();

      // S = Q K^T
      f32x4 s[4] = {};
#pragma unroll
      for (int ks = 0; ks < 2; ++ks)
#pragma unroll
        for (int nt = 0; nt < 4; ++nt) {
          bf16x8 kb = *reinterpret_cast<const bf16x8*>(&Klds[(nt * 16 + lr) * 72 + ks * 32 + lg * 8]);
          s[nt] = mfma16(qf[ks], kb, s[nt]);
        }
#pragma unroll
      for (int nt = 0; nt < 4; ++nt) s[nt] *= 0.125f;

      // online softmax (rows owned per-reg; 16-lane row reduce)
      float alpha[4];
#pragma unroll
      for (int r = 0; r < 4; ++r) {
        float pm = fmaxf(fmaxf(s[0][r], s[1][r]), fmaxf(s[2][r], s[3][r]));
#pragma unroll
        for (int off = 1; off < 16; off <<= 1)
          pm = fmaxf(pm, __shfl_xor(pm, off, 64));
        const float mn = fmaxf(m[r], pm);
        const float al = __expf(m[r] - mn);
        float pr[4], rs = 0.f;
#pragma unroll
        for (int nt = 0; nt < 4; ++nt) {
          pr[nt] = __expf(s[nt][r] - mn);
          rs += pr[nt];
        }
#pragma unroll
        for (int off = 1; off < 16; off <<= 1)
          rs += __shfl_xor(rs, off, 64);
        lsum[r] = lsum[r] * al + rs;
        m[r] = mn;
        alpha[r] = al;
#pragma unroll
        for (int nt = 0; nt < 4; ++nt)
          Plds[(wv * 16 + lg * 4 + r) * 72 + nt * 16 + lr] = (bf16)pr[nt];
      }

#pragma unroll
      for (int dt = 0; dt < 4; ++dt) {
        O[dt][0] *= alpha[0]; O[dt][1] *= alpha[1];
        O[dt][2] *= alpha[2]; O[dt][3] *= alpha[3];
      }

      // O += P V  (P from LDS as A-frag; V^T from LDS as B-frag)
#pragma unroll
      for (int ks = 0; ks < 2; ++ks) {
        bf16x8 pa = *reinterpret_cast<const bf16x8*>(&Plds[(wv * 16 + lr) * 72 + ks * 32 + lg * 8]);
#pragma unroll
        for (int dt = 0; dt < 4; ++dt) {
          bf16x8 vb = *reinterpret_cast<const bf16x8*>(&VT[(dt * 16 + lr) * 72 + ks * 32 + lg * 8]);
          O[dt] = mfma16(pa, vb, O[dt]);
        }
      }
    }
#pragma unroll
    for (int r = 0; r < 4; ++r) {
      const float inv = 1.0f / lsum[r];
#pragma unroll
      for (int dt = 0; dt < 4; ++dt) Ofin[dt][r] += O[dt][r] * inv;
    }
  }

#pragma unroll
  for (int dt = 0; dt < 4; ++dt)
#pragma unroll
    for (int r = 0; r < 4; ++r)
      Mg[(size_t)(qrow + lg * 4 + r) * CDIM + h * 64 + dt * 16 + lr] = (bf16)Ofin[dt][r];
}

extern "C" void kernel_launch(void* const* d_in, const int* in_sizes, int n_in,
                              void* d_out, int out_size, void* d_ws, size_t ws_size,
                              hipStream_t stream) {
  const float* hidden = (const float*)d_in[0];
  const float* mask   = (const float*)d_in[1];
  const float* Wq     = (const float*)d_in[2];
  const float* Wk     = (const float*)d_in[3];
  const float* Wv     = (const float*)d_in[4];
  const float* Wo     = (const float*)d_in[5];
  const float* bo     = (const float*)d_in[6];
  float* out = (float*)d_out;

  char* ws = (char*)d_ws;
  bf16* hb  = (bf16*)(ws);             // 4096x1280
  bf16* wqb = (bf16*)(ws + 10485760);  // 1280x1280
  bf16* wkb = (bf16*)(ws + 13762560);
  bf16* wvb = (bf16*)(ws + 17039360);
  bf16* wob = (bf16*)(ws + 20316160);
  bf16* Qb  = (bf16*)(ws + 23592960);  // 4096x1280
  bf16* Kbg = (bf16*)(ws + 34078720);  // 2048x1280
  bf16* Vbg = (bf16*)(ws + 39321600);
  bf16* Kf  = (bf16*)(ws + 44564480);
  bf16* Vf  = (bf16*)(ws + 49807360);
  bf16* Mg  = hb;  // alias: hidden-bf16 dead after projections

  cvt_kernel<<<dim3(5120), 256, 0, stream>>>(hidden, hb, 5242880 / 4);
  cvt_kernel<<<dim3(1600), 256, 0, stream>>>(Wq, wqb, 1638400 / 4);
  cvt_kernel<<<dim3(1600), 256, 0, stream>>>(Wk, wkb, 1638400 / 4);
  cvt_kernel<<<dim3(1600), 256, 0, stream>>>(Wv, wvb, 1638400 / 4);
  cvt_kernel<<<dim3(1600), 256, 0, stream>>>(Wo, wob, 1638400 / 4);

  gemm_bt<<<dim3(10, 32), 256, 0, stream>>>(hb, wqb, Qb, nullptr, nullptr, nullptr);
  gemm_bt<<<dim3(10, 16), 256, 0, stream>>>(hb, wkb, Kbg, nullptr, nullptr, nullptr);
  gemm_bt<<<dim3(10, 16), 256, 0, stream>>>(hb, wvb, Vbg, nullptr, nullptr, nullptr);
  gemm_bt<<<dim3(10, 16), 256, 0, stream>>>(hb + (size_t)2048 * CDIM, wkb, Kf, nullptr, mask, nullptr);
  gemm_bt<<<dim3(10, 16), 256, 0, stream>>>(hb + (size_t)2048 * CDIM, wvb, Vf, nullptr, mask, nullptr);

  attn_kernel<<<dim3(32, 20, 2), 256, 0, stream>>>(Qb, Kbg, Vbg, Kf, Vf, Mg);

  gemm_bt<<<dim3(10, 32), 256, 0, stream>>>(Mg, wob, nullptr, out, nullptr, bo);
}

// Round 2
// 227.233 us; speedup vs baseline: 2.4093x; 2.4093x over previous
//
#include <hip/hip_runtime.h>
#include <hip/hip_bf16.h>

typedef __bf16 bf16;
typedef __bf16 bf16x8 __attribute__((ext_vector_type(8)));
typedef __bf16 bf16x4 __attribute__((ext_vector_type(4)));
typedef float f32x4 __attribute__((ext_vector_type(4)));

#define CDIM 1280

static __device__ __forceinline__ f32x4 mfma16(bf16x8 a, bf16x8 b, f32x4 c) {
  return __builtin_amdgcn_mfma_f32_16x16x32_bf16(a, b, c, 0, 0, 0);
}

static __device__ __forceinline__ void gload_lds(const bf16* g, bf16* l) {
  __builtin_amdgcn_global_load_lds(
      (const __attribute__((address_space(1))) void*)g,
      (__attribute__((address_space(3))) void*)l, 16, 0, 0);
}

// ---- fused f32 -> bf16 conversion for hidden + 4 weights ----
__global__ __launch_bounds__(256) void cvt_all(const float* __restrict__ h,
                                               const float* __restrict__ wq,
                                               const float* __restrict__ wk,
                                               const float* __restrict__ wv,
                                               const float* __restrict__ wo,
                                               bf16* __restrict__ hb, bf16* __restrict__ wqb,
                                               bf16* __restrict__ wkb, bf16* __restrict__ wvb,
                                               bf16* __restrict__ wob) {
  int id = blockIdx.x * 256 + threadIdx.x;  // float4 index, total 2949120
  const float* src; bf16* dst; int off;
  if (id < 1310720) { src = h; dst = hb; off = id; }
  else {
    int t = id - 1310720;
    int w = t / 409600; off = t % 409600;
    src = (w == 0) ? wq : (w == 1) ? wk : (w == 2) ? wv : wo;
    dst = (w == 0) ? wqb : (w == 1) ? wkb : (w == 2) ? wvb : wob;
  }
  float4 v = reinterpret_cast<const float4*>(src)[off];
  bf16x4 o;
  o[0] = (bf16)v.x; o[1] = (bf16)v.y; o[2] = (bf16)v.z; o[3] = (bf16)v.w;
  reinterpret_cast<bf16x4*>(dst)[off] = o;
}

// ---- fused QKV projection: X(4096x1280) x [Wq|Wk|Wv]^T ----
// blockIdx.x 0..29 -> weight select + 128-col tile. K rows>=2048 and all V rows
// get gate (V only rows>=2048). V written transposed: Vt[bh][d][key].
__global__ __launch_bounds__(256) void qkv_gemm(const bf16* __restrict__ X,
                                                const bf16* __restrict__ Wq,
                                                const bf16* __restrict__ Wk,
                                                const bf16* __restrict__ Wv,
                                                const float* __restrict__ mask,
                                                bf16* __restrict__ Qb,
                                                bf16* __restrict__ Kb,
                                                bf16* __restrict__ Vt) {
  __shared__ bf16 Al[128 * 64];
  __shared__ bf16 Bl[128 * 64];
  const int tid = threadIdx.x, lane = tid & 63, wv = tid >> 6;
  const int lr = lane & 15, lg = lane >> 4;
  const int xb = blockIdx.x, by = blockIdx.y;
  const int wsel = xb / 10;            // 0=Q 1=K 2=V
  const int cb = (xb % 10) * 128;
  const bf16* W = (wsel == 0) ? Wq : (wsel == 1) ? Wk : Wv;
  const int strow = tid >> 3, stchk = tid & 7;
  f32x4 acc[4][4] = {};
  for (int kt = 0; kt < 20; ++kt) {
    __syncthreads();
#pragma unroll
    for (int i = 0; i < 4; ++i) {
      gload_lds(X + (size_t)(by * 128 + i * 32 + strow) * CDIM + kt * 64 + stchk * 8,
                &Al[(i * 256 + tid) * 8]);
      gload_lds(W + (size_t)(cb + i * 32 + strow) * CDIM + kt * 64 + stchk * 8,
                &Bl[(i * 256 + tid) * 8]);
    }
    __syncthreads();
#pragma unroll
    for (int kk = 0; kk < 2; ++kk) {
      bf16x8 a[4], b[4];
#pragma unroll
      for (int i = 0; i < 4; ++i) {
        a[i] = *(const bf16x8*)&Al[((wv >> 1) * 64 + i * 16 + lr) * 64 + kk * 32 + lg * 8];
        b[i] = *(const bf16x8*)&Bl[((wv & 1) * 64 + i * 16 + lr) * 64 + kk * 32 + lg * 8];
      }
#pragma unroll
      for (int i = 0; i < 4; ++i)
#pragma unroll
        for (int j = 0; j < 4; ++j)
          acc[i][j] = mfma16(a[i], b[j], acc[i][j]);
    }
  }
  const int rbase = by * 128 + (wv >> 1) * 64;
  const int cbase = cb + (wv & 1) * 64;
  if (wsel == 2) {  // V -> Vt[bh][d][key], gated rows >= 2048
#pragma unroll
    for (int i = 0; i < 4; ++i)
#pragma unroll
      for (int r = 0; r < 4; ++r) {
        const int row = rbase + i * 16 + lg * 4 + r;
        const float g = (row >= 2048) ? mask[row - 2048] : 1.0f;
        const int br = row >> 11, bb = (row >> 10) & 1, key = row & 1023;
#pragma unroll
        for (int j = 0; j < 4; ++j) {
          const int col = cbase + j * 16 + lr;
          const int hh = col >> 6, d = col & 63;
          Vt[(size_t)(br * 40 + bb * 20 + hh) * 65536 + d * 1024 + key] =
              (bf16)(acc[i][j][r] * g);
        }
      }
  } else {
    bf16* Y = (wsel == 0) ? Qb : Kb;
    const bool gated = (wsel == 1);
#pragma unroll
    for (int i = 0; i < 4; ++i)
#pragma unroll
      for (int r = 0; r < 4; ++r) {
        const int row = rbase + i * 16 + lg * 4 + r;
        const float g = (gated && row >= 2048) ? mask[row - 2048] : 1.0f;
#pragma unroll
        for (int j = 0; j < 4; ++j)
          Y[(size_t)row * CDIM + cbase + j * 16 + lr] = (bf16)(acc[i][j][r] * g);
      }
  }
}

// ---- flash attention, swapped QK^T, both branches ----
__global__ __launch_bounds__(256) void attn_kernel(const bf16* __restrict__ Q,
                                                   const bf16* __restrict__ K,
                                                   const bf16* __restrict__ Vt,
                                                   bf16* __restrict__ Mg) {
  __shared__ bf16 Kl[64 * 64];
  __shared__ bf16 Vl[64 * 64];
  __shared__ bf16 Pl[4 * 16 * 64];
  const int tid = threadIdx.x, lane = tid & 63, wv = tid >> 6;
  const int lr = lane & 15, lg = lane >> 4;
  // bijective XCD-chunked swizzle (nwg = 1280, 1280 % 8 == 0)
  const int bid = blockIdx.x;
  const int sb = (bid & 7) * 160 + (bid >> 3);
  const int qt = sb & 31, hh = (sb >> 5) % 20, b = sb / 640;
  const int qrow = b * 2048 + qt * 64 + wv * 16;
  const int strow = tid >> 3, stchk = tid & 7;

  bf16x8 qf0, qf1;
  {
    const bf16* qp = Q + (size_t)(qrow + lr) * CDIM + hh * 64 + lg * 8;
    qf0 = *(const bf16x8*)qp;
    qf1 = *(const bf16x8*)(qp + 32);
  }

  f32x4 Ofin[4] = {};
  for (int br = 0; br < 2; ++br) {
    const bf16* Kbase = K + (size_t)(br * 2048 + b * 1024) * CDIM + hh * 64;
    const bf16* Vbase = Vt + (size_t)(br * 40 + b * 20 + hh) * 65536;
    float m = -INFINITY, lsum = 0.f;
    f32x4 O[4] = {};
    for (int kt = 0; kt < 16; ++kt) {
      __syncthreads();
      // stage K tile [64 key][64 d] and V^T tile [64 d][64 key], XOR-preswizzled source
#pragma unroll
      for (int i = 0; i < 2; ++i) {
        const int row = i * 32 + strow;
        gload_lds(Kbase + (size_t)(kt * 64 + row) * CDIM + (stchk ^ (row & 7)) * 8,
                  &Kl[(i * 256 + tid) * 8]);
        gload_lds(Vbase + (size_t)row * 1024 + kt * 64 + (stchk ^ (row & 7)) * 8,
                  &Vl[(i * 256 + tid) * 8]);
      }
      __syncthreads();
      // S^T[key][q] = K . Q^T   (lane owns q = lr; keys kb*16 + lg*4 + r)
      f32x4 st[4];
#pragma unroll
      for (int kb = 0; kb < 4; ++kb) {
        const int row = kb * 16 + lr;
        bf16x8 k0 = *(const bf16x8*)&Kl[row * 64 + ((lg) ^ (lr & 7)) * 8];
        bf16x8 k1 = *(const bf16x8*)&Kl[row * 64 + ((4 + lg) ^ (lr & 7)) * 8];
        f32x4 z = {};
        z = mfma16(k0, qf0, z);
        z = mfma16(k1, qf1, z);
        st[kb] = z;
      }
      // online softmax, all in-lane + 2 shuffles
      float pm = -INFINITY;
#pragma unroll
      for (int kb = 0; kb < 4; ++kb)
#pragma unroll
        for (int r = 0; r < 4; ++r) { st[kb][r] *= 0.125f; pm = fmaxf(pm, st[kb][r]); }
      pm = fmaxf(pm, __shfl_xor(pm, 16, 64));
      pm = fmaxf(pm, __shfl_xor(pm, 32, 64));
      const float mn = fmaxf(m, pm);
      const float al = __expf(m - mn);
      float rs = 0.f;
      float p[16];
#pragma unroll
      for (int kb = 0; kb < 4; ++kb)
#pragma unroll
        for (int r = 0; r < 4; ++r) { float e = __expf(st[kb][r] - mn); p[kb * 4 + r] = e; rs += e; }
      rs += __shfl_xor(rs, 16, 64);
      rs += __shfl_xor(rs, 32, 64);
      lsum = lsum * al + rs;
      m = mn;
      // store P[q][key] swizzled (per-wave slice, wave-synchronous LDS)
#pragma unroll
      for (int kb = 0; kb < 4; ++kb) {
        const int chunk = (kb * 2 + (lg >> 1)) ^ (lr & 7);
        const int base = wv * 1024 + lr * 64 + chunk * 8 + (lg & 1) * 4;
        bf16x4 pk;
        pk[0] = (bf16)p[kb * 4 + 0]; pk[1] = (bf16)p[kb * 4 + 1];
        pk[2] = (bf16)p[kb * 4 + 2]; pk[3] = (bf16)p[kb * 4 + 3];
        *(bf16x4*)&Pl[base] = pk;
      }
      // rescale O (O rows q = lg*4 + r)
      float alr[4];
#pragma unroll
      for (int r = 0; r < 4; ++r) alr[r] = __shfl(al, lg * 4 + r, 64);
#pragma unroll
      for (int dt = 0; dt < 4; ++dt) {
        O[dt][0] *= alr[0]; O[dt][1] *= alr[1];
        O[dt][2] *= alr[2]; O[dt][3] *= alr[3];
      }
      // O += P V
      bf16x8 pa0 = *(const bf16x8*)&Pl[wv * 1024 + lr * 64 + ((lg) ^ (lr & 7)) * 8];
      bf16x8 pa1 = *(const bf16x8*)&Pl[wv * 1024 + lr * 64 + ((4 + lg) ^ (lr & 7)) * 8];
#pragma unroll
      for (int dt = 0; dt < 4; ++dt) {
        const int row = dt * 16 + lr;
        bf16x8 v0 = *(const bf16x8*)&Vl[row * 64 + ((lg) ^ (lr & 7)) * 8];
        bf16x8 v1 = *(const bf16x8*)&Vl[row * 64 + ((4 + lg) ^ (lr & 7)) * 8];
        O[dt] = mfma16(pa0, v0, O[dt]);
        O[dt] = mfma16(pa1, v1, O[dt]);
      }
    }
    const float invl = 1.0f / lsum;
    float ivr[4];
#pragma unroll
    for (int r = 0; r < 4; ++r) ivr[r] = __shfl(invl, lg * 4 + r, 64);
#pragma unroll
    for (int dt = 0; dt < 4; ++dt) {
      Ofin[dt][0] += O[dt][0] * ivr[0]; Ofin[dt][1] += O[dt][1] * ivr[1];
      Ofin[dt][2] += O[dt][2] * ivr[2]; Ofin[dt][3] += O[dt][3] * ivr[3];
    }
  }
#pragma unroll
  for (int dt = 0; dt < 4; ++dt)
#pragma unroll
    for (int r = 0; r < 4; ++r)
      Mg[(size_t)(qrow + lg * 4 + r) * CDIM + hh * 64 + dt * 16 + lr] = (bf16)Ofin[dt][r];
}

// ---- final projection: Mg(4096x1280) x Wo^T + bias -> f32 out ----
__global__ __launch_bounds__(256) void out_gemm(const bf16* __restrict__ X,
                                                const bf16* __restrict__ W,
                                                const float* __restrict__ bias,
                                                float* __restrict__ Y) {
  __shared__ bf16 Al[128 * 64];
  __shared__ bf16 Bl[128 * 64];
  const int tid = threadIdx.x, lane = tid & 63, wv = tid >> 6;
  const int lr = lane & 15, lg = lane >> 4;
  const int cb = blockIdx.x * 128, by = blockIdx.y;
  const int strow = tid >> 3, stchk = tid & 7;
  f32x4 acc[4][4] = {};
  for (int kt = 0; kt < 20; ++kt) {
    __syncthreads();
#pragma unroll
    for (int i = 0; i < 4; ++i) {
      gload_lds(X + (size_t)(by * 128 + i * 32 + strow) * CDIM + kt * 64 + stchk * 8,
                &Al[(i * 256 + tid) * 8]);
      gload_lds(W + (size_t)(cb + i * 32 + strow) * CDIM + kt * 64 + stchk * 8,
                &Bl[(i * 256 + tid) * 8]);
    }
    __syncthreads();
#pragma unroll
    for (int kk = 0; kk < 2; ++kk) {
      bf16x8 a[4], b[4];
#pragma unroll
      for (int i = 0; i < 4; ++i) {
        a[i] = *(const bf16x8*)&Al[((wv >> 1) * 64 + i * 16 + lr) * 64 + kk * 32 + lg * 8];
        b[i] = *(const bf16x8*)&Bl[((wv & 1) * 64 + i * 16 + lr) * 64 + kk * 32 + lg * 8];
      }
#pragma unroll
      for (int i = 0; i < 4; ++i)
#pragma unroll
        for (int j = 0; j < 4; ++j)
          acc[i][j] = mfma16(a[i], b[j], acc[i][j]);
    }
  }
  const int rbase = by * 128 + (wv >> 1) * 64;
  const int cbase = cb + (wv & 1) * 64;
#pragma unroll
  for (int i = 0; i < 4; ++i)
#pragma unroll
    for (int r = 0; r < 4; ++r) {
      const int row = rbase + i * 16 + lg * 4 + r;
#pragma unroll
      for (int j = 0; j < 4; ++j) {
        const int col = cbase + j * 16 + lr;
        Y[(size_t)row * CDIM + col] = acc[i][j][r] + bias[col];
      }
    }
}

extern "C" void kernel_launch(void* const* d_in, const int* in_sizes, int n_in,
                              void* d_out, int out_size, void* d_ws, size_t ws_size,
                              hipStream_t stream) {
  const float* hidden = (const float*)d_in[0];
  const float* mask   = (const float*)d_in[1];
  const float* Wq     = (const float*)d_in[2];
  const float* Wk     = (const float*)d_in[3];
  const float* Wv     = (const float*)d_in[4];
  const float* Wo     = (const float*)d_in[5];
  const float* bo     = (const float*)d_in[6];
  float* out = (float*)d_out;

  char* ws = (char*)d_ws;
  bf16* hb  = (bf16*)(ws);             // 4096x1280 (aliased as Mg after projections)
  bf16* wqb = (bf16*)(ws + 10485760);
  bf16* wkb = (bf16*)(ws + 13762560);
  bf16* wvb = (bf16*)(ws + 17039360);
  bf16* wob = (bf16*)(ws + 20316160);
  bf16* Qb  = (bf16*)(ws + 23592960);  // 4096x1280
  bf16* Kb  = (bf16*)(ws + 34078720);  // 4096x1280 (bg rows 0..2047, face gated 2048..4095)
  bf16* Vt  = (bf16*)(ws + 44564480);  // [80][64][1024] transposed V, gated
  bf16* Mg  = hb;

  cvt_all<<<dim3(11520), 256, 0, stream>>>(hidden, Wq, Wk, Wv, Wo, hb, wqb, wkb, wvb, wob);
  qkv_gemm<<<dim3(30, 32), 256, 0, stream>>>(hb, wqb, wkb, wvb, mask, Qb, Kb, Vt);
  attn_kernel<<<dim3(1280), 256, 0, stream>>>(Qb, Kb, Vt, Mg);
  out_gemm<<<dim3(10, 32), 256, 0, stream>>>(Mg, wob, bo, out);
}

// Round 3
// 226.089 us; speedup vs baseline: 2.4214x; 1.0051x over previous
//
#include <hip/hip_runtime.h>
#include <hip/hip_bf16.h>

typedef __bf16 bf16;
typedef __bf16 bf16x8 __attribute__((ext_vector_type(8)));
typedef __bf16 bf16x4 __attribute__((ext_vector_type(4)));
typedef float f32x4 __attribute__((ext_vector_type(4)));

#define CDIM 1280

static __device__ __forceinline__ f32x4 mfma16(bf16x8 a, bf16x8 b, f32x4 c) {
  return __builtin_amdgcn_mfma_f32_16x16x32_bf16(a, b, c, 0, 0, 0);
}

static __device__ __forceinline__ void gload_lds(const bf16* g, bf16* l) {
  __builtin_amdgcn_global_load_lds(
      (const __attribute__((address_space(1))) void*)g,
      (__attribute__((address_space(3))) void*)l, 16, 0, 0);
}

static __device__ __forceinline__ float fexp2(float x) {
#if __has_builtin(__builtin_amdgcn_exp2f)
  return __builtin_amdgcn_exp2f(x);
#else
  return __expf(x * 0.6931471805599453f);
#endif
}

// ---- fused f32 -> bf16 conversion for hidden + 4 weights ----
__global__ __launch_bounds__(256) void cvt_all(const float* __restrict__ h,
                                               const float* __restrict__ wq,
                                               const float* __restrict__ wk,
                                               const float* __restrict__ wv,
                                               const float* __restrict__ wo,
                                               bf16* __restrict__ hb, bf16* __restrict__ wqb,
                                               bf16* __restrict__ wkb, bf16* __restrict__ wvb,
                                               bf16* __restrict__ wob) {
  int id = blockIdx.x * 256 + threadIdx.x;  // float4 index, total 2949120
  const float* src; bf16* dst; int off;
  if (id < 1310720) { src = h; dst = hb; off = id; }
  else {
    int t = id - 1310720;
    int w = t / 409600; off = t % 409600;
    src = (w == 0) ? wq : (w == 1) ? wk : (w == 2) ? wv : wo;
    dst = (w == 0) ? wqb : (w == 1) ? wkb : (w == 2) ? wvb : wob;
  }
  float4 v = reinterpret_cast<const float4*>(src)[off];
  bf16x4 o;
  o[0] = (bf16)v.x; o[1] = (bf16)v.y; o[2] = (bf16)v.z; o[3] = (bf16)v.w;
  reinterpret_cast<bf16x4*>(dst)[off] = o;
}

// ---- fused QKV projection: X(4096x1280) x [Wq|Wk|Wv]^T ----
__global__ __launch_bounds__(256) void qkv_gemm(const bf16* __restrict__ X,
                                                const bf16* __restrict__ Wq,
                                                const bf16* __restrict__ Wk,
                                                const bf16* __restrict__ Wv,
                                                const float* __restrict__ mask,
                                                bf16* __restrict__ Qb,
                                                bf16* __restrict__ Kb,
                                                bf16* __restrict__ Vt) {
  __shared__ bf16 Al[128 * 64];
  __shared__ bf16 Bl[128 * 64];
  const int tid = threadIdx.x, lane = tid & 63, wv = tid >> 6;
  const int lr = lane & 15, lg = lane >> 4;
  const int xb = blockIdx.x, by = blockIdx.y;
  const int wsel = xb / 10;            // 0=Q 1=K 2=V
  const int cb = (xb % 10) * 128;
  const bf16* W = (wsel == 0) ? Wq : (wsel == 1) ? Wk : Wv;
  const int strow = tid >> 3, stchk = tid & 7;
  f32x4 acc[4][4] = {};
  for (int kt = 0; kt < 20; ++kt) {
    __syncthreads();
#pragma unroll
    for (int i = 0; i < 4; ++i) {
      gload_lds(X + (size_t)(by * 128 + i * 32 + strow) * CDIM + kt * 64 + stchk * 8,
                &Al[(i * 256 + tid) * 8]);
      gload_lds(W + (size_t)(cb + i * 32 + strow) * CDIM + kt * 64 + stchk * 8,
                &Bl[(i * 256 + tid) * 8]);
    }
    __syncthreads();
#pragma unroll
    for (int kk = 0; kk < 2; ++kk) {
      bf16x8 a[4], b[4];
#pragma unroll
      for (int i = 0; i < 4; ++i) {
        a[i] = *(const bf16x8*)&Al[((wv >> 1) * 64 + i * 16 + lr) * 64 + kk * 32 + lg * 8];
        b[i] = *(const bf16x8*)&Bl[((wv & 1) * 64 + i * 16 + lr) * 64 + kk * 32 + lg * 8];
      }
#pragma unroll
      for (int i = 0; i < 4; ++i)
#pragma unroll
        for (int j = 0; j < 4; ++j)
          acc[i][j] = mfma16(a[i], b[j], acc[i][j]);
    }
  }
  const int rbase = by * 128 + (wv >> 1) * 64;
  const int cbase = cb + (wv & 1) * 64;
  if (wsel == 2) {  // V -> Vt[bh][d][key], gated rows >= 2048
#pragma unroll
    for (int i = 0; i < 4; ++i)
#pragma unroll
      for (int r = 0; r < 4; ++r) {
        const int row = rbase + i * 16 + lg * 4 + r;
        const float g = (row >= 2048) ? mask[row - 2048] : 1.0f;
        const int br = row >> 11, bb = (row >> 10) & 1, key = row & 1023;
#pragma unroll
        for (int j = 0; j < 4; ++j) {
          const int col = cbase + j * 16 + lr;
          const int hh = col >> 6, d = col & 63;
          Vt[(size_t)(br * 40 + bb * 20 + hh) * 65536 + d * 1024 + key] =
              (bf16)(acc[i][j][r] * g);
        }
      }
  } else {
    bf16* Y = (wsel == 0) ? Qb : Kb;
    const bool gated = (wsel == 1);
#pragma unroll
    for (int i = 0; i < 4; ++i)
#pragma unroll
      for (int r = 0; r < 4; ++r) {
        const int row = rbase + i * 16 + lg * 4 + r;
        const float g = (gated && row >= 2048) ? mask[row - 2048] : 1.0f;
#pragma unroll
        for (int j = 0; j < 4; ++j)
          Y[(size_t)row * CDIM + cbase + j * 16 + lr] = (bf16)(acc[i][j][r] * g);
      }
  }
}

// ---- flash attention: swapped QK^T, exp2 softmax, defer-max, 2-phase dbuf ----
__global__ __launch_bounds__(256) void attn_kernel(const bf16* __restrict__ Q,
                                                   const bf16* __restrict__ K,
                                                   const bf16* __restrict__ Vt,
                                                   bf16* __restrict__ Mg) {
  __shared__ bf16 Kl[2][64 * 64];
  __shared__ bf16 Vl[2][64 * 64];
  __shared__ bf16 Pl[4 * 16 * 64];
  const int tid = threadIdx.x, lane = tid & 63, wv = tid >> 6;
  const int lr = lane & 15, lg = lane >> 4;
  // bijective XCD-chunked swizzle (nwg = 1280, 1280 % 8 == 0)
  const int bid = blockIdx.x;
  const int sb = (bid & 7) * 160 + (bid >> 3);
  const int qt = sb & 31, hh = (sb >> 5) % 20, b = sb / 640;
  const int qrow = b * 2048 + qt * 64 + wv * 16;
  const int strow = tid >> 3, stchk = tid & 7;

  const bf16* Kb0 = K + (size_t)(b * 1024) * CDIM + hh * 64;
  const bf16* Vb0 = Vt + (size_t)(b * 20 + hh) * 65536;

  // Q fragments, pre-scaled by 0.125 * log2(e)  -> logits in exp2 domain
  bf16x8 qf0, qf1;
  {
    const float SL2E = 0.125f * 1.4426950408889634f;
    const bf16* qp = Q + (size_t)(qrow + lr) * CDIM + hh * 64 + lg * 8;
    bf16x8 r0 = *(const bf16x8*)qp;
    bf16x8 r1 = *(const bf16x8*)(qp + 32);
#pragma unroll
    for (int j = 0; j < 8; ++j) {
      qf0[j] = (bf16)((float)r0[j] * SL2E);
      qf1[j] = (bf16)((float)r1[j] * SL2E);
    }
  }

  auto stage = [&](int t, int buf) {
    const int br = t >> 4, kt = t & 15;
    const bf16* Kp = Kb0 + (size_t)br * 2048 * CDIM;
    const bf16* Vp = Vb0 + (size_t)br * 40 * 65536;
#pragma unroll
    for (int i = 0; i < 2; ++i) {
      const int row = i * 32 + strow;
      gload_lds(Kp + (size_t)(kt * 64 + row) * CDIM + (stchk ^ (row & 7)) * 8,
                &Kl[buf][(i * 256 + tid) * 8]);
      gload_lds(Vp + (size_t)row * 1024 + kt * 64 + (stchk ^ (row & 7)) * 8,
                &Vl[buf][(i * 256 + tid) * 8]);
    }
  };

  float m = -INFINITY, l = 0.f;
  f32x4 O[4] = {};
  f32x4 Ofin[4] = {};

  stage(0, 0);
  __syncthreads();

  for (int t = 0; t < 32; ++t) {
    const int cur = t & 1;
    if (t < 31) stage(t + 1, cur ^ 1);  // issue-early: latency hides under compute

    // S^T[key][q] = K . Q^T   (lane owns q = lr; keys kb*16 + lg*4 + r)
    f32x4 st4[4];
#pragma unroll
    for (int kb = 0; kb < 4; ++kb) {
      const int row = kb * 16 + lr;
      bf16x8 k0 = *(const bf16x8*)&Kl[cur][row * 64 + ((lg) ^ (lr & 7)) * 8];
      bf16x8 k1 = *(const bf16x8*)&Kl[cur][row * 64 + ((4 + lg) ^ (lr & 7)) * 8];
      f32x4 z = {};
      z = mfma16(k0, qf0, z);
      z = mfma16(k1, qf1, z);
      st4[kb] = z;
    }

    // online softmax in exp2 domain, defer-max (THR=8 -> P <= 256)
    float pm = -INFINITY;
#pragma unroll
    for (int kb = 0; kb < 4; ++kb)
#pragma unroll
      for (int r = 0; r < 4; ++r) pm = fmaxf(pm, st4[kb][r]);
    pm = fmaxf(pm, __shfl_xor(pm, 16, 64));
    pm = fmaxf(pm, __shfl_xor(pm, 32, 64));

    float p[16], rs = 0.f;
    if (__all(pm <= m + 8.f)) {
#pragma unroll
      for (int kb = 0; kb < 4; ++kb)
#pragma unroll
        for (int r = 0; r < 4; ++r) {
          float e = fexp2(st4[kb][r] - m);
          p[kb * 4 + r] = e; rs += e;
        }
      rs += __shfl_xor(rs, 16, 64);
      rs += __shfl_xor(rs, 32, 64);
      l += rs;
    } else {
      const float mn = fmaxf(m, pm);
      const float al = fexp2(m - mn);
#pragma unroll
      for (int kb = 0; kb < 4; ++kb)
#pragma unroll
        for (int r = 0; r < 4; ++r) {
          float e = fexp2(st4[kb][r] - mn);
          p[kb * 4 + r] = e; rs += e;
        }
      rs += __shfl_xor(rs, 16, 64);
      rs += __shfl_xor(rs, 32, 64);
      l = l * al + rs;
      m = mn;
      float alr[4];
#pragma unroll
      for (int r = 0; r < 4; ++r) alr[r] = __shfl(al, lg * 4 + r, 64);
#pragma unroll
      for (int dt = 0; dt < 4; ++dt) {
        O[dt][0] *= alr[0]; O[dt][1] *= alr[1];
        O[dt][2] *= alr[2]; O[dt][3] *= alr[3];
      }
    }

    // store P[q][key] swizzled (per-wave slice, wave-synchronous LDS)
#pragma unroll
    for (int kb = 0; kb < 4; ++kb) {
      const int chunk = (kb * 2 + (lg >> 1)) ^ (lr & 7);
      const int base = wv * 1024 + lr * 64 + chunk * 8 + (lg & 1) * 4;
      bf16x4 pk;
      pk[0] = (bf16)p[kb * 4 + 0]; pk[1] = (bf16)p[kb * 4 + 1];
      pk[2] = (bf16)p[kb * 4 + 2]; pk[3] = (bf16)p[kb * 4 + 3];
      *(bf16x4*)&Pl[base] = pk;
    }

    // O += P V
    bf16x8 pa0 = *(const bf16x8*)&Pl[wv * 1024 + lr * 64 + ((lg) ^ (lr & 7)) * 8];
    bf16x8 pa1 = *(const bf16x8*)&Pl[wv * 1024 + lr * 64 + ((4 + lg) ^ (lr & 7)) * 8];
#pragma unroll
    for (int dt = 0; dt < 4; ++dt) {
      const int row = dt * 16 + lr;
      bf16x8 v0 = *(const bf16x8*)&Vl[cur][row * 64 + ((lg) ^ (lr & 7)) * 8];
      bf16x8 v1 = *(const bf16x8*)&Vl[cur][row * 64 + ((4 + lg) ^ (lr & 7)) * 8];
      O[dt] = mfma16(pa0, v0, O[dt]);
      O[dt] = mfma16(pa1, v1, O[dt]);
    }

    if (t == 15 || t == 31) {  // end of branch: merge with 1/l
      const float invl = 1.0f / l;
      float ivr[4];
#pragma unroll
      for (int r = 0; r < 4; ++r) ivr[r] = __shfl(invl, lg * 4 + r, 64);
#pragma unroll
      for (int dt = 0; dt < 4; ++dt) {
        Ofin[dt][0] += O[dt][0] * ivr[0]; Ofin[dt][1] += O[dt][1] * ivr[1];
        Ofin[dt][2] += O[dt][2] * ivr[2]; Ofin[dt][3] += O[dt][3] * ivr[3];
      }
      if (t == 15) {
        m = -INFINITY; l = 0.f;
#pragma unroll
        for (int dt = 0; dt < 4; ++dt) O[dt] = f32x4{};
      }
    }
    __syncthreads();  // staged tile t+1 ready; buf[cur] free for overwrite
  }

#pragma unroll
  for (int dt = 0; dt < 4; ++dt)
#pragma unroll
    for (int r = 0; r < 4; ++r)
      Mg[(size_t)(qrow + lg * 4 + r) * CDIM + hh * 64 + dt * 16 + lr] = (bf16)Ofin[dt][r];
}

// ---- final projection: Mg(4096x1280) x Wo^T + bias -> f32 out ----
__global__ __launch_bounds__(256) void out_gemm(const bf16* __restrict__ X,
                                                const bf16* __restrict__ W,
                                                const float* __restrict__ bias,
                                                float* __restrict__ Y) {
  __shared__ bf16 Al[128 * 64];
  __shared__ bf16 Bl[128 * 64];
  const int tid = threadIdx.x, lane = tid & 63, wv = tid >> 6;
  const int lr = lane & 15, lg = lane >> 4;
  const int cb = blockIdx.x * 128, by = blockIdx.y;
  const int strow = tid >> 3, stchk = tid & 7;
  f32x4 acc[4][4] = {};
  for (int kt = 0; kt < 20; ++kt) {
    __syncthreads();
#pragma unroll
    for (int i = 0; i < 4; ++i) {
      gload_lds(X + (size_t)(by * 128 + i * 32 + strow) * CDIM + kt * 64 + stchk * 8,
                &Al[(i * 256 + tid) * 8]);
      gload_lds(W + (size_t)(cb + i * 32 + strow) * CDIM + kt * 64 + stchk * 8,
                &Bl[(i * 256 + tid) * 8]);
    }
    __syncthreads();
#pragma unroll
    for (int kk = 0; kk < 2; ++kk) {
      bf16x8 a[4], b[4];
#pragma unroll
      for (int i = 0; i < 4; ++i) {
        a[i] = *(const bf16x8*)&Al[((wv >> 1) * 64 + i * 16 + lr) * 64 + kk * 32 + lg * 8];
        b[i] = *(const bf16x8*)&Bl[((wv & 1) * 64 + i * 16 + lr) * 64 + kk * 32 + lg * 8];
      }
#pragma unroll
      for (int i = 0; i < 4; ++i)
#pragma unroll
        for (int j = 0; j < 4; ++j)
          acc[i][j] = mfma16(a[i], b[j], acc[i][j]);
    }
  }
  const int rbase = by * 128 + (wv >> 1) * 64;
  const int cbase = cb + (wv & 1) * 64;
#pragma unroll
  for (int i = 0; i < 4; ++i)
#pragma unroll
    for (int r = 0; r < 4; ++r) {
      const int row = rbase + i * 16 + lg * 4 + r;
#pragma unroll
      for (int j = 0; j < 4; ++j) {
        const int col = cbase + j * 16 + lr;
        Y[(size_t)row * CDIM + col] = acc[i][j][r] + bias[col];
      }
    }
}

extern "C" void kernel_launch(void* const* d_in, const int* in_sizes, int n_in,
                              void* d_out, int out_size, void* d_ws, size_t ws_size,
                              hipStream_t stream) {
  const float* hidden = (const float*)d_in[0];
  const float* mask   = (const float*)d_in[1];
  const float* Wq     = (const float*)d_in[2];
  const float* Wk     = (const float*)d_in[3];
  const float* Wv     = (const float*)d_in[4];
  const float* Wo     = (const float*)d_in[5];
  const float* bo     = (const float*)d_in[6];
  float* out = (float*)d_out;

  char* ws = (char*)d_ws;
  bf16* hb  = (bf16*)(ws);             // 4096x1280 (aliased as Mg after projections)
  bf16* wqb = (bf16*)(ws + 10485760);
  bf16* wkb = (bf16*)(ws + 13762560);
  bf16* wvb = (bf16*)(ws + 17039360);
  bf16* wob = (bf16*)(ws + 20316160);
  bf16* Qb  = (bf16*)(ws + 23592960);  // 4096x1280
  bf16* Kb  = (bf16*)(ws + 34078720);  // 4096x1280 (bg rows 0..2047, face gated 2048..4095)
  bf16* Vt  = (bf16*)(ws + 44564480);  // [80][64][1024] transposed V, gated
  bf16* Mg  = hb;

  cvt_all<<<dim3(11520), 256, 0, stream>>>(hidden, Wq, Wk, Wv, Wo, hb, wqb, wkb, wvb, wob);
  qkv_gemm<<<dim3(30, 32), 256, 0, stream>>>(hb, wqb, wkb, wvb, mask, Qb, Kb, Vt);
  attn_kernel<<<dim3(1280), 256, 0, stream>>>(Qb, Kb, Vt, Mg);
  out_gemm<<<dim3(10, 32), 256, 0, stream>>>(Mg, wob, bo, out);
}